// Round 4
// baseline (109.003 us; speedup 1.0000x reference)
//
#include <hip/hip_runtime.h>
#include <math.h>

#define H    512
#define LQ   64
#define LA   100
#define LAP  128
#define L2E2 2.885390081777927f   /* 2*log2(e): exp2(a1'+q2') = e^{2x} */

using short8  = __attribute__((ext_vector_type(8))) short;
using floatx4 = __attribute__((ext_vector_type(4))) float;

__device__ __forceinline__ unsigned short f2bf(float f) {
    unsigned int u = __float_as_uint(f);
    u += 0x7fffu + ((u >> 16) & 1u);          // RNE
    return (unsigned short)(u >> 16);
}
__device__ __forceinline__ unsigned int packbf2(float a, float b) {
    return (unsigned int)f2bf(a) | ((unsigned int)f2bf(b) << 16);
}

// ---------------------------------------------------------------------------
// prep: build bf16 8KB tiles (64 rows x 64 k) in global memory with the
// fragment-friendly layout: element (r, k) at byte
//   r*128 + (((k>>3) ^ (r&7))*16) + (k&7)*2
// so each MFMA fragment (8 consecutive k of one row) is 16 CONTIGUOUS bytes.
//   blocks 0..127  : A1 tiles (mt 0..15, kc 0..7) from c1; kc+8 tile = c1^2
//   blocks 128..327: A2 tiles (mt 0..24, kc 0..7) from c2 (1600 = 25*64 rows)
//   blocks 328..455: B1 tiles (nt 0..7, kc 0..15): W^T of Wa (kc<8) / Waq
//   blocks 456..519: B2 tiles (nt 0..7, kc 0..7):  W^T of Wq
// ---------------------------------------------------------------------------
__global__ __launch_bounds__(256) void prep_kernel(
    const float* __restrict__ c1, const float* __restrict__ c2,
    const float* __restrict__ Wq, const float* __restrict__ Wa,
    const float* __restrict__ Waq,
    unsigned short* __restrict__ A1sw, unsigned short* __restrict__ A2sw,
    unsigned short* __restrict__ B1sw, unsigned short* __restrict__ B2sw)
{
    __shared__ __align__(16) float lt[64][68];   // B-transpose scratch
    const int bid = blockIdx.x, t = threadIdx.x;

    if (bid < 328) {            // ---- A path: row-major read, swizzled write
        const bool isA1 = bid < 128;
        int mt, kc; const float* X;
        if (isA1) { mt = bid >> 3; kc = bid & 7; X = c1; }
        else      { int b2 = bid - 128; mt = b2 >> 3; kc = b2 & 7; X = c2; }
#pragma unroll
        for (int i = 0; i < 4; ++i) {
            int idx = i * 256 + t;
            int r = idx >> 4, c4 = idx & 15;
            float4 v = *(const float4*)(X + (size_t)(mt * 64 + r) * H + kc * 64 + c4 * 4);
            int bytepos = r * 128 + (((c4 >> 1) ^ (r & 7)) * 16) + (c4 & 1) * 8;
            if (isA1) {
                unsigned short* t1 = A1sw + (size_t)(mt * 16 + kc) * 4096;
                *(uint2*)((char*)t1 + bytepos) = make_uint2(packbf2(v.x, v.y), packbf2(v.z, v.w));
                unsigned short* t2 = A1sw + (size_t)(mt * 16 + kc + 8) * 4096;
                *(uint2*)((char*)t2 + bytepos) =
                    make_uint2(packbf2(v.x * v.x, v.y * v.y), packbf2(v.z * v.z, v.w * v.w));
            } else {
                unsigned short* t1 = A2sw + (size_t)(mt * 8 + kc) * 4096;
                *(uint2*)((char*)t1 + bytepos) = make_uint2(packbf2(v.x, v.y), packbf2(v.z, v.w));
            }
        }
    } else {                    // ---- B path: transpose W[k][n] -> [n][k] tiles
        int b3 = bid - 328;
        const bool isB1 = b3 < 128;
        int nt, kc; const float* W; int k0;
        if (isB1) { nt = b3 >> 4; kc = b3 & 15; W = (kc < 8) ? Wa : Waq; k0 = (kc & 7) * 64; }
        else      { int b4 = b3 - 128; nt = b4 >> 3; kc = b4 & 7; W = Wq; k0 = kc * 64; }
        const int n0 = nt * 64;
#pragma unroll
        for (int i = 0; i < 4; ++i) {
            int idx = i * 256 + t;
            int k = idx >> 4, n4 = idx & 15;
            float4 v = *(const float4*)(W + (size_t)(k0 + k) * H + n0 + n4 * 4);
            lt[n4 * 4 + 0][k] = v.x;
            lt[n4 * 4 + 1][k] = v.y;
            lt[n4 * 4 + 2][k] = v.z;
            lt[n4 * 4 + 3][k] = v.w;
        }
        __syncthreads();
#pragma unroll
        for (int i = 0; i < 4; ++i) {
            int idx = i * 256 + t;
            int r = idx >> 4, c4 = idx & 15;
            float4 v = *(const float4*)&lt[r][c4 * 4];
            int bytepos = r * 128 + (((c4 >> 1) ^ (r & 7)) * 16) + (c4 & 1) * 8;
            unsigned short* tile = isB1 ? B1sw + (size_t)(nt * 16 + kc) * 4096
                                        : B2sw + (size_t)(nt * 8 + kc) * 4096;
            *(uint2*)((char*)tile + bytepos) = make_uint2(packbf2(v.x, v.y), packbf2(v.z, v.w));
        }
    }
}

// ---------------------------------------------------------------------------
// gemm: LDS-FREE, BARRIER-FREE. Each lane loads its MFMA fragments directly
// global->VGPR (tiles are fragment-contiguous 16B chunks, L2-resident).
// Compiler pipelines loads across K freely — no vmcnt(0) barrier drains.
//   blocks 0..127  : a1 = [c1|c1^2] @ [Wa;Waq]^T (BM=64, K=1024)
//   blocks 128..231: q2 = c2 @ Wq^T (BM=128, K=512), 13x8 tiles, rows<1600
// 232 blocks total -> every CU gets at most 1 block (no straggler round).
// ---------------------------------------------------------------------------
__global__ __launch_bounds__(256) void gemm_kernel(
    const unsigned short* __restrict__ A1sw, const unsigned short* __restrict__ A2sw,
    const unsigned short* __restrict__ B1sw, const unsigned short* __restrict__ B2sw,
    const float* __restrict__ bq, const float* __restrict__ ba,
    const float* __restrict__ baq,
    float* __restrict__ a1, float* __restrict__ q2t)
{
    const int bid  = blockIdx.x;
    const int t    = threadIdx.x;
    const int w    = t >> 6, lane = t & 63;
    const int q    = lane >> 4, ln = lane & 15;

    if (bid < 128) {            // ---------------- a1 path: BM=64, nk=16
        const int mt = bid >> 3, nt = bid & 7;
        const char* Ab = (const char*)(A1sw + (size_t)(mt * 16) * 4096)
                         + (w * 16 + ln) * 128;
        const char* Bb = (const char*)(B1sw + (size_t)(nt * 16) * 4096)
                         + ln * 128;
        floatx4 acc[4];
#pragma unroll
        for (int j = 0; j < 4; ++j) acc[j] = (floatx4){0.f, 0.f, 0.f, 0.f};

#pragma unroll 2
        for (int kc = 0; kc < 16; ++kc) {
            const char* ga = Ab + kc * 8192;
            const char* gb = Bb + kc * 8192;
#pragma unroll
            for (int s = 0; s < 2; ++s) {
                const int off = ((s * 4 + q) ^ (ln & 7)) * 16;
                short8 af = *(const short8*)(ga + off);
#pragma unroll
                for (int j = 0; j < 4; ++j) {
                    short8 bf = *(const short8*)(gb + j * 2048 + off);
                    acc[j] = __builtin_amdgcn_mfma_f32_16x16x32_bf16(af, bf, acc[j], 0, 0, 0);
                }
            }
        }
        const int m0 = mt * 64, n0 = nt * 64;
#pragma unroll
        for (int j = 0; j < 4; ++j) {
            const int N = n0 + j * 16 + ln;
            const float bias = ba[N] + baq[N];
#pragma unroll
            for (int r = 0; r < 4; ++r) {
                const int R = m0 + w * 16 + q * 4 + r;
                a1[(size_t)R * H + N] = (acc[j][r] + bias) * L2E2;
            }
        }
    } else {                    // ---------------- q2 path: BM=128, nk=8
        const int b2 = bid - 128;
        const int mt = b2 >> 3, nt = b2 & 7;     // mt 0..12 (rows mt*128..+127)
        const int tile64 = mt * 2 + (w >> 1);    // 64-row tile index in A2sw
        const char* A0p = (const char*)(A2sw + (size_t)(tile64 * 8) * 4096)
                          + ((w & 1) * 32 + ln) * 128;        // rh=0 rows
        const char* A1p = A0p + 16 * 128;                      // rh=1 rows
        const char* Bb  = (const char*)(B2sw + (size_t)(nt * 8) * 4096)
                          + ln * 128;
        floatx4 acc[2][4];
#pragma unroll
        for (int rh = 0; rh < 2; ++rh)
#pragma unroll
            for (int j = 0; j < 4; ++j) acc[rh][j] = (floatx4){0.f, 0.f, 0.f, 0.f};

#pragma unroll 2
        for (int kc = 0; kc < 8; ++kc) {
            const char* gb = Bb + kc * 8192;
#pragma unroll
            for (int s = 0; s < 2; ++s) {
                const int off = ((s * 4 + q) ^ (ln & 7)) * 16;
                short8 af0 = *(const short8*)(A0p + kc * 8192 + off);
                short8 af1 = *(const short8*)(A1p + kc * 8192 + off);
#pragma unroll
                for (int j = 0; j < 4; ++j) {
                    short8 bf = *(const short8*)(gb + j * 2048 + off);
                    acc[0][j] = __builtin_amdgcn_mfma_f32_16x16x32_bf16(af0, bf, acc[0][j], 0, 0, 0);
                    acc[1][j] = __builtin_amdgcn_mfma_f32_16x16x32_bf16(af1, bf, acc[1][j], 0, 0, 0);
                }
            }
        }
        const int n0 = nt * 64;
#pragma unroll
        for (int rh = 0; rh < 2; ++rh) {
#pragma unroll
            for (int r = 0; r < 4; ++r) {
                const int R = mt * 128 + w * 32 + rh * 16 + q * 4 + r;
                if (R < 1600) {                   // rows 1600..1663 are pad
                    const int bb = (R * 5243) >> 19;     // R/100
                    const int aa = R - bb * 100;
                    float* dst = q2t + (size_t)bb * (H * LAP) + aa;
#pragma unroll
                    for (int j = 0; j < 4; ++j) {
                        const int N = n0 + j * 16 + ln;
                        dst[(size_t)N * LAP] = (acc[rh][j][r] + bq[N]) * L2E2;
                    }
                }
            }
        }
    }
}

// ---------------------------------------------------------------------------
// score+entropy: block = (b, q-group of 4), 1024 threads = (hh in [0,8), a in
// [0,128)). 4 h per step: float4 LDS reads (b128 broadcast); loop is
// transcendental-bound (2 trans/element). score = bv + sum(wv) - 2*R.
// ---------------------------------------------------------------------------
__global__ __launch_bounds__(1024) void score_entropy_kernel(
    const float* __restrict__ a1, const float* __restrict__ q2t,
    const float* __restrict__ wvp, const float* __restrict__ bvp,
    float* __restrict__ out)
{
    __shared__ __align__(16) float a1s[4][H];
    __shared__ __align__(16) float wvs[H];
    __shared__ __align__(16) float part[8][LAP][4];

    const int t  = threadIdx.x;
    const int b  = blockIdx.x >> 4;
    const int qg = blockIdx.x & 15;

    for (int i = t; i < 4 * H; i += 1024) {
        int q = i >> 9, h = i & (H - 1);
        a1s[q][h] = a1[(size_t)(b * LQ + (qg << 2) + q) * H + h];
    }
    if (t < H) wvs[t] = wvp[t];
    __syncthreads();

    const int a  = t & 127;
    const int hh = t >> 7;
    const int hb = hh * 64;
    const float* q2p = q2t + (size_t)b * (H * LAP) + (size_t)hb * LAP + a;

    float R0 = 0.f, R1 = 0.f, R2 = 0.f, R3 = 0.f;
#define TERM(Rq, Aq, vv, ww) \
    Rq = fmaf(ww, __builtin_amdgcn_rcpf(__builtin_amdgcn_exp2f((Aq) + (vv)) + 1.f), Rq)
#pragma unroll 4
    for (int i = 0; i < 16; ++i) {
        const int h4 = i * 4;
        float4 wv4 = *(const float4*)&wvs[hb + h4];
        float4 A0 = *(const float4*)&a1s[0][hb + h4];
        float4 A1 = *(const float4*)&a1s[1][hb + h4];
        float4 A2 = *(const float4*)&a1s[2][hb + h4];
        float4 A3 = *(const float4*)&a1s[3][hb + h4];
        float v0 = q2p[(size_t)(h4 + 0) * LAP];
        float v1 = q2p[(size_t)(h4 + 1) * LAP];
        float v2 = q2p[(size_t)(h4 + 2) * LAP];
        float v3 = q2p[(size_t)(h4 + 3) * LAP];
        TERM(R0, A0.x, v0, wv4.x); TERM(R0, A0.y, v1, wv4.y);
        TERM(R0, A0.z, v2, wv4.z); TERM(R0, A0.w, v3, wv4.w);
        TERM(R1, A1.x, v0, wv4.x); TERM(R1, A1.y, v1, wv4.y);
        TERM(R1, A1.z, v2, wv4.z); TERM(R1, A1.w, v3, wv4.w);
        TERM(R2, A2.x, v0, wv4.x); TERM(R2, A2.y, v1, wv4.y);
        TERM(R2, A2.z, v2, wv4.z); TERM(R2, A2.w, v3, wv4.w);
        TERM(R3, A3.x, v0, wv4.x); TERM(R3, A3.y, v1, wv4.y);
        TERM(R3, A3.z, v2, wv4.z); TERM(R3, A3.w, v3, wv4.w);
    }
#undef TERM
    *(float4*)(&part[hh][a][0]) = make_float4(R0, R1, R2, R3);
    __syncthreads();

    if (t < 256) {
        const int l = t & 63, q = t >> 6;        // wave q handles local q
        float ws = 0.f;
#pragma unroll
        for (int i = 0; i < 8; ++i) ws += wvs[l + (i << 6)];
#pragma unroll
        for (int o = 32; o; o >>= 1) ws += __shfl_xor(ws, o);

        const float base = bvp[0] + ws;
        float s1 = 0.f, s2 = 0.f;
#pragma unroll
        for (int i = 0; i < 8; ++i) s1 += part[i][l][q];
        const bool act2 = l < (LA - 64);
        if (act2) {
#pragma unroll
            for (int i = 0; i < 8; ++i) s2 += part[i][l + 64][q];
        }
        float sc1 = base - 2.f * s1;
        float sc2 = act2 ? (base - 2.f * s2) : -INFINITY;
        float m = fmaxf(sc1, sc2);
#pragma unroll
        for (int o = 32; o; o >>= 1) m = fmaxf(m, __shfl_xor(m, o));

        const float L2E = 1.4426950408889634f;
        float e1 = __builtin_amdgcn_exp2f((sc1 - m) * L2E);
        float e2 = act2 ? __builtin_amdgcn_exp2f((sc2 - m) * L2E) : 0.f;
        float Z = e1 + e2;
        float S = e1 * sc1 + (act2 ? e2 * sc2 : 0.f);
#pragma unroll
        for (int o = 32; o; o >>= 1) {
            Z += __shfl_xor(Z, o);
            S += __shfl_xor(S, o);
        }
        if (l == 0) out[b * LQ + (qg << 2) + q] = m + logf(Z) - S / Z;
    }
}

extern "C" void kernel_launch(void* const* d_in, const int* in_sizes, int n_in,
                              void* d_out, int out_size, void* d_ws, size_t ws_size,
                              hipStream_t stream) {
    const float* c1  = (const float*)d_in[0];
    const float* c2  = (const float*)d_in[1];
    const float* Wq  = (const float*)d_in[3];
    const float* bq  = (const float*)d_in[4];
    const float* Wa  = (const float*)d_in[5];
    const float* ba  = (const float*)d_in[6];
    const float* Waq = (const float*)d_in[7];
    const float* baq = (const float*)d_in[8];
    const float* Wv  = (const float*)d_in[9];
    const float* bv  = (const float*)d_in[10];
    float* out = (float*)d_out;

    float* a1  = (float*)d_ws;                                    // 2 MB
    float* q2t = a1 + (size_t)1024 * 512;                         // 4 MB
    unsigned short* A1sw = (unsigned short*)(q2t + (size_t)16 * 512 * 128);
    unsigned short* A2sw = A1sw + (size_t)16 * 16 * 4096;         // 2 MB
    unsigned short* B1sw = A2sw + (size_t)26 * 8 * 4096;          // (1 pad tile row)
    unsigned short* B2sw = B1sw + (size_t)8 * 16 * 4096;          // 1 MB

    prep_kernel<<<dim3(520), dim3(256), 0, stream>>>(c1, c2, Wq, Wa, Waq,
                                                     A1sw, A2sw, B1sw, B2sw);
    gemm_kernel<<<dim3(232), dim3(256), 0, stream>>>(A1sw, A2sw, B1sw, B2sw,
                                                     bq, ba, baq, a1, q2t);
    score_entropy_kernel<<<dim3(256), dim3(1024), 0, stream>>>(a1, q2t, Wv, bv, out);
}